// Round 3
// baseline (1609.720 us; speedup 1.0000x reference)
//
#include <hip/hip_runtime.h>
#include <hip/hip_fp16.h>

// ---------------------------------------------------------------------------
// GCN 2-layer (PyG GCNConv) on MI355X — R17.
// R16 post-mortem: deltas landed (agg1 57.5->52.1us, total 287.5, VGPR 28,
// WRITE 0.8MB). agg1 counters: VALU 74%, HBM 39%, occ 67% -> NOT at a
// roofline; ~470 VALU/wave vs ~180 needed + 6x hs overfetch (157MB vs 25.6
// ideal; 12.8MB hs thrashes 4MB/XCD L2 under time-random gathers).
// R17 single structural delta: invert aggregation.
//   - finalize sort key: dest-node -> SOURCE-BUCKET (row>>9); csr2 = int2
//     (cl<<17|row, f32 w) = binned entry verbatim; offset[] dropped.
//   - agg1: one 1024-thr block per 512-node bucket, 512x64 f32 acc in LDS
//     (128KB, ok per gfx950 160KB/CU); stream csr2 (sorted by src bucket ->
//     concurrent gathers hit a ~64KB hot hs slice), lane l gathers f16x2
//     (features 2l,2l+1) and ds_add_f32 into slots l / 32+l of acc[cl]
//     (bank=lane -> 2-way, free). ~5 VALU+1DS+1VMEM per edge vs ~15 VALU.
//     Per-node epilogue (self+relu+W2 dot) amortized per block.
//   - agg2: same LDS-accumulate shape (acc2[512]); h2s 400KB is L2-hot.
//   - edge weights now f32 end-to-end (no f16 w rounding).
// hist/scan/scan_tot/scatter/gemm byte-identical to R16.
// Predict: agg1 52->~22us, FETCH 157->60-110MB, occ ~50%, small
// LDS_BANK_CONFLICT; total 287->~250-260us; absmax <= 9.77e-4.
// Failure signature: agg1 >40us + high LDS conflicts => ds_add serialization.
// ---------------------------------------------------------------------------

#define BSHIFT 9
#define BSIZE 512            // nodes per bucket
#define NBUCKET 256          // max buckets (requires N <= 131072)

typedef _Float16 f16x8 __attribute__((ext_vector_type(8)));
typedef float    f32x4 __attribute__((ext_vector_type(4)));

#define LDS_FADD(p, v) __hip_atomic_fetch_add((p), (v), __ATOMIC_RELAXED, \
                                              __HIP_MEMORY_SCOPE_WORKGROUP)

// ---------------- CSR build ----------------

__global__ __launch_bounds__(1024) void k_hist(const int* __restrict__ col,
                                               int* __restrict__ hist, int E4) {
    __shared__ int h[NBUCKET];
    int t = threadIdx.x, bl = blockIdx.x;
    if (t < NBUCKET) h[t] = 0;
    __syncthreads();
#pragma unroll
    for (int i = 0; i < 4; ++i) {
        int idx = bl * 4096 + i * 1024 + t;
        if (idx < E4) {
            int4 c = ((const int4*)col)[idx];
            atomicAdd(&h[c.x >> BSHIFT], 1);
            atomicAdd(&h[c.y >> BSHIFT], 1);
            atomicAdd(&h[c.z >> BSHIFT], 1);
            atomicAdd(&h[c.w >> BSHIFT], 1);
        }
    }
    __syncthreads();
    if (t < NBUCKET) hist[bl * NBUCKET + t] = h[t];
}

__global__ __launch_bounds__(256) void k_scan_bucket(const int* __restrict__ hist,
                                                     int* __restrict__ histS,
                                                     int* __restrict__ tot, int nbl) {
    __shared__ int A[2][256];
    int b = blockIdx.x, t = threadIdx.x;
    A[0][t] = (t < nbl) ? hist[t * NBUCKET + b] : 0;
    __syncthreads();
    int src = 0;
    for (int off = 1; off < 256; off <<= 1) {
        A[1 - src][t] = A[src][t] + ((t >= off) ? A[src][t - off] : 0);
        src ^= 1;
        __syncthreads();
    }
    if (t < nbl) histS[b * nbl + t] = (t > 0) ? A[src][t - 1] : 0;
    if (t == 0) tot[b] = A[src][nbl - 1];
}

__global__ __launch_bounds__(256) void k_scan_tot(const int* __restrict__ tot,
                                                  int* __restrict__ base) {
    __shared__ int A[2][NBUCKET];
    int t = threadIdx.x;
    A[0][t] = tot[t];
    __syncthreads();
    int src = 0;
    for (int off = 1; off < NBUCKET; off <<= 1) {
        A[1 - src][t] = A[src][t] + ((t >= off) ? A[src][t - off] : 0);
        src ^= 1;
        __syncthreads();
    }
    base[t] = (t > 0) ? A[src][t - 1] : 0;
    if (t == 255) base[NBUCKET] = A[src][255];
}

__global__ __launch_bounds__(1024) void k_scatter(const int* __restrict__ ei,
                                                  const float* __restrict__ ea,
                                                  const int* __restrict__ histS,
                                                  const int* __restrict__ base,
                                                  int2* __restrict__ binned,
                                                  int E, int E4, int nbl) {
    __shared__ int cur[NBUCKET];
    int t = threadIdx.x, bl = blockIdx.x;
    if (t < NBUCKET) cur[t] = base[t] + histS[t * nbl + bl];
    __syncthreads();
#pragma unroll
    for (int i = 0; i < 4; ++i) {
        int idx = bl * 4096 + i * 1024 + t;
        if (idx < E4) {
            int4   r = ((const int4*)ei)[idx];
            int4   c = ((const int4*)(ei + E))[idx];
            float4 w = ((const float4*)ea)[idx];
            int p;
            p = atomicAdd(&cur[c.x >> BSHIFT], 1);
            binned[p] = make_int2(((c.x & (BSIZE - 1)) << 17) | r.x, __float_as_int(w.x));
            p = atomicAdd(&cur[c.y >> BSHIFT], 1);
            binned[p] = make_int2(((c.y & (BSIZE - 1)) << 17) | r.y, __float_as_int(w.y));
            p = atomicAdd(&cur[c.z >> BSHIFT], 1);
            binned[p] = make_int2(((c.z & (BSIZE - 1)) << 17) | r.z, __float_as_int(w.z));
            p = atomicAdd(&cur[c.w >> BSHIFT], 1);
            binned[p] = make_int2(((c.w & (BSIZE - 1)) << 17) | r.w, __float_as_int(w.w));
        }
    }
}

// R17: counting-sort each dst-bucket's edges by SOURCE bucket (row>>9).
// Emits csr2[p] = binned entry (cl<<17|row, f32 w), plus per-node dinv.
__global__ __launch_bounds__(1024) void k_finalize(const int2* __restrict__ binned,
                                                   const int* __restrict__ base,
                                                   int2* __restrict__ csr2,
                                                   float* __restrict__ dinv,
                                                   int N) {
    __shared__ int   cnt[NBUCKET];
    __shared__ float fsum[BSIZE];
    __shared__ int   inc[2][NBUCKET];
    __shared__ int   cur[NBUCKET];
    int b = blockIdx.x, t = threadIdx.x;
    int e0 = base[b], e1 = base[b + 1];
    if (t < NBUCKET) cnt[t] = 0;
    for (int i = t; i < BSIZE; i += 1024) fsum[i] = 0.f;
    __syncthreads();
    for (int e = e0 + t; e < e1; e += 1024) {
        int2 ed = binned[e];
        int srcb = (ed.x & 0x1FFFF) >> BSHIFT;
        unsigned cl = ((unsigned)ed.x) >> 17;
        atomicAdd(&cnt[srcb], 1);
        atomicAdd(&fsum[cl], __int_as_float(ed.y));
    }
    __syncthreads();
    if (t < NBUCKET) inc[0][t] = cnt[t];
    __syncthreads();
    int src = 0;
    for (int off = 1; off < NBUCKET; off <<= 1) {
        if (t < NBUCKET)
            inc[1 - src][t] = inc[src][t] + ((t >= off) ? inc[src][t - off] : 0);
        src ^= 1;
        __syncthreads();
    }
    if (t < NBUCKET) cur[t] = e0 + ((t > 0) ? inc[src][t - 1] : 0);
    int nodeBase = b << BSHIFT;
    for (int i = t; i < BSIZE; i += 1024) {
        int node = nodeBase + i;
        if (node < N) dinv[node] = rsqrtf(1.0f + fsum[i]);
    }
    __syncthreads();
    for (int e = e0 + t; e < e1; e += 1024) {
        int2 ed = binned[e];
        int srcb = (ed.x & 0x1FFFF) >> BSHIFT;
        int p = atomicAdd(&cur[srcb], 1);
        csr2[p] = ed;
    }
}

// ---------------- dense compute (identical to R16) ----------------

__global__ __launch_bounds__(256) void k_gemm_mfma(const float* __restrict__ x,
                                                   const float* __restrict__ W1,
                                                   const float* __restrict__ dinv,
                                                   __half* __restrict__ hs, int n) {
    __shared__ _Float16 xh[64][136];
    __shared__ _Float16 wTh[64][136];
    int t = threadIdx.x;
    int nodeBase = blockIdx.x * 64;

    for (int i = t; i < 2048; i += 256) {
        int r = i >> 5, c4 = i & 31;
        int node = nodeBase + r;
        float4 v = make_float4(0.f, 0.f, 0.f, 0.f);
        if (node < n) v = ((const float4*)x)[node * 32 + c4];
        _Float16* dst = &xh[r][c4 * 4];
        dst[0] = (_Float16)v.x; dst[1] = (_Float16)v.y;
        dst[2] = (_Float16)v.z; dst[3] = (_Float16)v.w;
    }
    for (int i = t; i < 2048; i += 256) {
        int k = i >> 4, c4 = i & 15;
        float4 v = ((const float4*)W1)[k * 16 + c4];
        wTh[c4 * 4 + 0][k] = (_Float16)v.x;
        wTh[c4 * 4 + 1][k] = (_Float16)v.y;
        wTh[c4 * 4 + 2][k] = (_Float16)v.z;
        wTh[c4 * 4 + 3][k] = (_Float16)v.w;
    }
    __syncthreads();

    int w = t >> 6, lane = t & 63;
    int m = lane & 15, quad = lane >> 4;

    f32x4 acc[4] = {{0.f,0.f,0.f,0.f},{0.f,0.f,0.f,0.f},
                    {0.f,0.f,0.f,0.f},{0.f,0.f,0.f,0.f}};
#pragma unroll
    for (int ks = 0; ks < 128; ks += 32) {
        f16x8 a = *(const f16x8*)&xh[w * 16 + m][ks + quad * 8];
#pragma unroll
        for (int ct = 0; ct < 4; ++ct) {
            f16x8 bfr = *(const f16x8*)&wTh[ct * 16 + m][ks + quad * 8];
            acc[ct] = __builtin_amdgcn_mfma_f32_16x16x32_f16(a, bfr, acc[ct], 0, 0, 0);
        }
    }

#pragma unroll
    for (int reg = 0; reg < 4; ++reg) {
        int node = nodeBase + w * 16 + quad * 4 + reg;
        if (node < n) {
            float dv = dinv[node];
#pragma unroll
            for (int ct = 0; ct < 4; ++ct) {
                float v = acc[ct][reg] * dv;
                hs[(size_t)node * 64 + ct * 16 + m] = __float2half_rn(v);
            }
        }
    }
}

// ---------------- DPP reduce helpers (hardware-verified in R16) ----------

__device__ __forceinline__ float dpp_ror8(float x) {
    return __int_as_float(__builtin_amdgcn_update_dpp(
        0, __float_as_int(x), 0x128, 0xF, 0xF, true));
}
template<int CTRL>
__device__ __forceinline__ float dpp_mov(float x) {
    return __int_as_float(__builtin_amdgcn_update_dpp(
        0, __float_as_int(x), CTRL, 0xF, 0xF, true));
}
__device__ __forceinline__ float swz_xor16(float x) {
    return __int_as_float(__builtin_amdgcn_ds_swizzle(__float_as_int(x), 0x401F));
}

// ---------------- agg1 (R17: LDS-accumulate per bucket) ----------------

__global__ __launch_bounds__(1024) void k_agg1(const __half* __restrict__ hs,
                                               const int* __restrict__ base,
                                               const int2* __restrict__ csr2,
                                               const float* __restrict__ dinv,
                                               const float* __restrict__ b1,
                                               const float* __restrict__ W2,
                                               float* __restrict__ h2s, int N) {
    __shared__ float acc[BSIZE * 64];      // 128 KB: acc[cl][slot]; feature 2l
                                           // -> slot l, 2l+1 -> slot 32+l
    int b = blockIdx.x, t = threadIdx.x;
    int e0 = base[b], e1 = base[b + 1];

    {   // zero 32768 floats, float4-wide
        float4* a4 = (float4*)acc;
        for (int i = t; i < BSIZE * 16; i += 1024)
            a4[i] = make_float4(0.f, 0.f, 0.f, 0.f);
    }
    __syncthreads();

    int w16  = t >> 6;                      // wave 0..15
    int lane = t & 63;
    int half = lane >> 5;                   // lanes 0-31: edge A, 32-63: edge B
    int l    = lane & 31;
    const char* hsL = (const char*)hs + (l << 2);   // + feature-pair byte off

    // stream edges: wave handles 8 edges (4 pairs) per round
    for (int bs = e0 + w16 * 8; bs < e1; bs += 16 * 8) {
#pragma unroll
        for (int u = 0; u < 4; ++u) {
            int idx = bs + 2 * u + half;    // uniform per half-wave
            if (idx < e1) {
                int2 ed = csr2[idx];
                unsigned cl  = ((unsigned)ed.x) >> 17;
                unsigned row = (unsigned)(ed.x & 0x1FFFF);
                float    wgt = __int_as_float(ed.y);
                unsigned hv  = *(const unsigned*)(hsL + (row << 7));
                float2 fv = __half22float2(*(const __half2*)&hv);
                LDS_FADD(&acc[cl * 64 + l],      wgt * fv.x);
                LDS_FADD(&acc[cl * 64 + 32 + l], wgt * fv.y);
            }
        }
    }
    __syncthreads();

    // epilogue: per node, lane = feature f; acc slot = (f>>1) | ((f&1)<<5)
    float bl = b1[lane];
    float wl = W2[lane];
    int slot = (lane >> 1) | ((lane & 1) << 5);
    int nodeBase = b << BSHIFT;
    for (int nn = w16; nn < BSIZE; nn += 16) {
        int node = nodeBase + nn;
        if (node >= N) break;               // uniform per wave
        float a    = acc[nn * 64 + slot];
        float self = __half2float(hs[node * 64 + lane]);
        float di   = dinv[node];
        float r = fmaxf(di * (a + self) + bl, 0.f) * wl;
        r += dpp_mov<0xB1>(r);              // xor 1
        r += dpp_mov<0x4E>(r);              // xor 2
        r += dpp_mov<0x141>(r);             // xor 4
        r += dpp_ror8(r);                   // xor 8
        r += swz_xor16(r);                  // xor 16
        r += __shfl_xor(r, 32);             // xor 32
        if (lane == 0) h2s[node] = di * r;
    }
}

// ---------------- agg2 (R17: LDS-accumulate per bucket) ----------------

__global__ __launch_bounds__(1024) void k_agg2(const float* __restrict__ h2s,
                                               const int* __restrict__ base,
                                               const int2* __restrict__ csr2,
                                               const float* __restrict__ dinv,
                                               const float* __restrict__ b2,
                                               float* __restrict__ out, int N) {
    __shared__ float acc2[BSIZE];
    int b = blockIdx.x, t = threadIdx.x;
    int e0 = base[b], e1 = base[b + 1];
    for (int i = t; i < BSIZE; i += 1024) acc2[i] = 0.f;
    __syncthreads();
    for (int e = e0 + t; e < e1; e += 1024) {
        int2 ed = csr2[e];
        unsigned cl  = ((unsigned)ed.x) >> 17;
        unsigned row = (unsigned)(ed.x & 0x1FFFF);
        LDS_FADD(&acc2[cl], __int_as_float(ed.y) * h2s[row]);
    }
    __syncthreads();
    int nodeBase = b << BSHIFT;
    float bias = b2[0];
    for (int i = t; i < BSIZE; i += 1024) {
        int node = nodeBase + i;
        if (node < N) out[node] = dinv[node] * (acc2[i] + h2s[node]) + bias;
    }
}

extern "C" void kernel_launch(void* const* d_in, const int* in_sizes, int n_in,
                              void* d_out, int out_size, void* d_ws, size_t ws_size,
                              hipStream_t stream) {
    const float* x  = (const float*)d_in[0];
    const int*   ei = (const int*)  d_in[1];
    const float* ea = (const float*)d_in[2];
    const float* W1 = (const float*)d_in[3];
    const float* b1 = (const float*)d_in[4];
    const float* W2 = (const float*)d_in[5];
    const float* b2 = (const float*)d_in[6];
    float* out = (float*)d_out;

    const int N  = in_sizes[0] / 128;   // 100000 (must be <= 131072)
    const int E  = in_sizes[2];         // 3200000
    const int E4 = E / 4;
    const int nbl  = (E4 + 4095) / 4096;        // 16384-edge chunks (196)
    const int nbkt = (N + BSIZE - 1) / BSIZE;   // active buckets (196)

    char* p = (char*)d_ws;
    auto alloc = [&](size_t bytes) -> void* {
        void* r = (void*)p;
        p += (bytes + 255) & ~(size_t)255;
        return r;
    };
    int*       hist   = (int*)      alloc((size_t)nbl * NBUCKET * 4);
    int*       histS  = (int*)      alloc((size_t)NBUCKET * nbl * 4);
    int*       tot    = (int*)      alloc((size_t)NBUCKET * 4);
    int*       base   = (int*)      alloc((size_t)(NBUCKET + 1) * 4);
    int2*      binned = (int2*)     alloc((size_t)E * 8);
    int2*      csr2   = (int2*)     alloc((size_t)E * 8);
    float*     dinv   = (float*)    alloc((size_t)N * 4);
    __half*    hs     = (__half*)   alloc((size_t)N * 64 * 2);
    float*     h2s    = (float*)    alloc((size_t)N * 4);

    const int nb_gemm = (N + 63) / 64;

    k_hist<<<nbl, 1024, 0, stream>>>(ei + E, hist, E4);
    k_scan_bucket<<<NBUCKET, 256, 0, stream>>>(hist, histS, tot, nbl);
    k_scan_tot<<<1, 256, 0, stream>>>(tot, base);
    k_scatter<<<nbl, 1024, 0, stream>>>(ei, ea, histS, base, binned, E, E4, nbl);
    k_finalize<<<nbkt, 1024, 0, stream>>>(binned, base, csr2, dinv, N);
    k_gemm_mfma<<<nb_gemm, 256, 0, stream>>>(x, W1, dinv, hs, N);
    k_agg1<<<nbkt, 1024, 0, stream>>>(hs, base, csr2, dinv, b1, W2, h2s, N);
    k_agg2<<<nbkt, 1024, 0, stream>>>(h2s, base, csr2, dinv, b2, out, N);
}

// Round 4
// 293.134 us; speedup vs baseline: 5.4914x; 5.4914x over previous
//
#include <hip/hip_runtime.h>
#include <hip/hip_fp16.h>

// ---------------------------------------------------------------------------
// GCN 2-layer (PyG GCNConv) on MI355X — R18.
// R17 post-mortem: LDS-accumulate inversion collapsed TLP (196 blocks x 16
// waves = 3136 waves vs 100K; 128KB LDS -> 1 block/CU) -> agg1 1390us at
// VALU 2.7% / HBM 0.9%: pure latency serialization. LESSON: this op needs
// >>20K concurrent waves; locality schemes that cut TLP lose.
// R18 = full revert to R16 (287.5us best; agg1 52.1us, VALU 74%, occ 67%)
// plus two confined agg1/agg2 deltas:
//   (1) 1024-thr blocks (same wave-per-node; 16 waves/block, grid 6250):
//       less block churn, occupancy 67 -> ~85%.
//   (2) peeled edge loop: nfull = deg>>5 unchecked rounds (scalar count) +
//       one checked tail round -> drops 4 cmp + 8 cndmask per full round.
// All other kernels byte-identical to R16.
// Predict: agg1 ~45us, FETCH ~157MB, WRITE ~0.8MB, total ~280us.
// If agg1 flat w/ occ up => latency floor => next: inline 8-slot MLP.
// If agg1 < #2 kernel => top-5 reveals next target.
// ---------------------------------------------------------------------------

#define BSHIFT 9
#define BSIZE 512            // nodes per bucket
#define NBUCKET 256          // max buckets (requires N <= 131072)

typedef _Float16 f16x8 __attribute__((ext_vector_type(8)));
typedef float    f32x4 __attribute__((ext_vector_type(4)));

// ---------------- CSR build (identical to R16) ----------------

__global__ __launch_bounds__(1024) void k_hist(const int* __restrict__ col,
                                               int* __restrict__ hist, int E4) {
    __shared__ int h[NBUCKET];
    int t = threadIdx.x, bl = blockIdx.x;
    if (t < NBUCKET) h[t] = 0;
    __syncthreads();
#pragma unroll
    for (int i = 0; i < 4; ++i) {
        int idx = bl * 4096 + i * 1024 + t;
        if (idx < E4) {
            int4 c = ((const int4*)col)[idx];
            atomicAdd(&h[c.x >> BSHIFT], 1);
            atomicAdd(&h[c.y >> BSHIFT], 1);
            atomicAdd(&h[c.z >> BSHIFT], 1);
            atomicAdd(&h[c.w >> BSHIFT], 1);
        }
    }
    __syncthreads();
    if (t < NBUCKET) hist[bl * NBUCKET + t] = h[t];
}

__global__ __launch_bounds__(256) void k_scan_bucket(const int* __restrict__ hist,
                                                     int* __restrict__ histS,
                                                     int* __restrict__ tot, int nbl) {
    __shared__ int A[2][256];
    int b = blockIdx.x, t = threadIdx.x;
    A[0][t] = (t < nbl) ? hist[t * NBUCKET + b] : 0;
    __syncthreads();
    int src = 0;
    for (int off = 1; off < 256; off <<= 1) {
        A[1 - src][t] = A[src][t] + ((t >= off) ? A[src][t - off] : 0);
        src ^= 1;
        __syncthreads();
    }
    if (t < nbl) histS[b * nbl + t] = (t > 0) ? A[src][t - 1] : 0;
    if (t == 0) tot[b] = A[src][nbl - 1];
}

__global__ __launch_bounds__(256) void k_scan_tot(const int* __restrict__ tot,
                                                  int* __restrict__ base) {
    __shared__ int A[2][NBUCKET];
    int t = threadIdx.x;
    A[0][t] = tot[t];
    __syncthreads();
    int src = 0;
    for (int off = 1; off < NBUCKET; off <<= 1) {
        A[1 - src][t] = A[src][t] + ((t >= off) ? A[src][t - off] : 0);
        src ^= 1;
        __syncthreads();
    }
    base[t] = (t > 0) ? A[src][t - 1] : 0;
    if (t == 255) base[NBUCKET] = A[src][255];
}

__global__ __launch_bounds__(1024) void k_scatter(const int* __restrict__ ei,
                                                  const float* __restrict__ ea,
                                                  const int* __restrict__ histS,
                                                  const int* __restrict__ base,
                                                  int2* __restrict__ binned,
                                                  int E, int E4, int nbl) {
    __shared__ int cur[NBUCKET];
    int t = threadIdx.x, bl = blockIdx.x;
    if (t < NBUCKET) cur[t] = base[t] + histS[t * nbl + bl];
    __syncthreads();
#pragma unroll
    for (int i = 0; i < 4; ++i) {
        int idx = bl * 4096 + i * 1024 + t;
        if (idx < E4) {
            int4   r = ((const int4*)ei)[idx];
            int4   c = ((const int4*)(ei + E))[idx];
            float4 w = ((const float4*)ea)[idx];
            int p;
            p = atomicAdd(&cur[c.x >> BSHIFT], 1);
            binned[p] = make_int2(((c.x & (BSIZE - 1)) << 17) | r.x, __float_as_int(w.x));
            p = atomicAdd(&cur[c.y >> BSHIFT], 1);
            binned[p] = make_int2(((c.y & (BSIZE - 1)) << 17) | r.y, __float_as_int(w.y));
            p = atomicAdd(&cur[c.z >> BSHIFT], 1);
            binned[p] = make_int2(((c.z & (BSIZE - 1)) << 17) | r.z, __float_as_int(w.z));
            p = atomicAdd(&cur[c.w >> BSHIFT], 1);
            binned[p] = make_int2(((c.w & (BSIZE - 1)) << 17) | r.w, __float_as_int(w.w));
        }
    }
}

__global__ __launch_bounds__(1024) void k_finalize(const int2* __restrict__ binned,
                                                   const int* __restrict__ base,
                                                   unsigned* __restrict__ csr,
                                                   int* __restrict__ offset,
                                                   float* __restrict__ dinv,
                                                   int N, int E) {
    __shared__ int   cnt[BSIZE];
    __shared__ float fsum[BSIZE];
    __shared__ int   inc[2][BSIZE];
    __shared__ int   cur[BSIZE];
    int b = blockIdx.x, t = threadIdx.x;
    int e0 = base[b], e1 = base[b + 1];
    for (int i = t; i < BSIZE; i += 1024) { cnt[i] = 0; fsum[i] = 0.f; }
    __syncthreads();
    for (int e = e0 + t; e < e1; e += 1024) {
        int2 ed = binned[e];
        unsigned cl = ((unsigned)ed.x) >> 17;
        atomicAdd(&cnt[cl], 1);
        atomicAdd(&fsum[cl], __int_as_float(ed.y));
    }
    __syncthreads();
    for (int i = t; i < BSIZE; i += 1024) inc[0][i] = cnt[i];
    __syncthreads();
    int src = 0;
    for (int off = 1; off < BSIZE; off <<= 1) {
        for (int i = t; i < BSIZE; i += 1024)
            inc[1 - src][i] = inc[src][i] + ((i >= off) ? inc[src][i - off] : 0);
        src ^= 1;
        __syncthreads();
    }
    int nodeBase = b << BSHIFT;
    for (int i = t; i < BSIZE; i += 1024) {
        int ex = (i > 0) ? inc[src][i - 1] : 0;
        cur[i] = e0 + ex;
        int node = nodeBase + i;
        if (node < N) {
            offset[node] = e0 + ex;
            dinv[node]   = rsqrtf(1.0f + fsum[i]);
        }
    }
    if (b == 0 && t == 0) offset[N] = E;
    __syncthreads();
    for (int e = e0 + t; e < e1; e += 1024) {
        int2 ed = binned[e];
        unsigned cl = ((unsigned)ed.x) >> 17;
        unsigned row = ((unsigned)ed.x) & 0x1FFFF;
        unsigned hb = (unsigned)__half_as_ushort(__float2half_rn(__int_as_float(ed.y))) & 0x7FFFu;
        int p = atomicAdd(&cur[cl], 1);
        csr[p] = (hb << 17) | row;
    }
}

// ---------------- dense compute (identical to R16) ----------------

__global__ __launch_bounds__(256) void k_gemm_mfma(const float* __restrict__ x,
                                                   const float* __restrict__ W1,
                                                   const float* __restrict__ dinv,
                                                   __half* __restrict__ hs, int n) {
    __shared__ _Float16 xh[64][136];
    __shared__ _Float16 wTh[64][136];
    int t = threadIdx.x;
    int nodeBase = blockIdx.x * 64;

    for (int i = t; i < 2048; i += 256) {
        int r = i >> 5, c4 = i & 31;
        int node = nodeBase + r;
        float4 v = make_float4(0.f, 0.f, 0.f, 0.f);
        if (node < n) v = ((const float4*)x)[node * 32 + c4];
        _Float16* dst = &xh[r][c4 * 4];
        dst[0] = (_Float16)v.x; dst[1] = (_Float16)v.y;
        dst[2] = (_Float16)v.z; dst[3] = (_Float16)v.w;
    }
    for (int i = t; i < 2048; i += 256) {
        int k = i >> 4, c4 = i & 15;
        float4 v = ((const float4*)W1)[k * 16 + c4];
        wTh[c4 * 4 + 0][k] = (_Float16)v.x;
        wTh[c4 * 4 + 1][k] = (_Float16)v.y;
        wTh[c4 * 4 + 2][k] = (_Float16)v.z;
        wTh[c4 * 4 + 3][k] = (_Float16)v.w;
    }
    __syncthreads();

    int w = t >> 6, lane = t & 63;
    int m = lane & 15, quad = lane >> 4;

    f32x4 acc[4] = {{0.f,0.f,0.f,0.f},{0.f,0.f,0.f,0.f},
                    {0.f,0.f,0.f,0.f},{0.f,0.f,0.f,0.f}};
#pragma unroll
    for (int ks = 0; ks < 128; ks += 32) {
        f16x8 a = *(const f16x8*)&xh[w * 16 + m][ks + quad * 8];
#pragma unroll
        for (int ct = 0; ct < 4; ++ct) {
            f16x8 bfr = *(const f16x8*)&wTh[ct * 16 + m][ks + quad * 8];
            acc[ct] = __builtin_amdgcn_mfma_f32_16x16x32_f16(a, bfr, acc[ct], 0, 0, 0);
        }
    }

#pragma unroll
    for (int reg = 0; reg < 4; ++reg) {
        int node = nodeBase + w * 16 + quad * 4 + reg;
        if (node < n) {
            float dv = dinv[node];
#pragma unroll
            for (int ct = 0; ct < 4; ++ct) {
                float v = acc[ct][reg] * dv;
                hs[(size_t)node * 64 + ct * 16 + m] = __float2half_rn(v);
            }
        }
    }
}

// ---------------- DPP reduce helpers (hardware-verified in R16) ----------

__device__ __forceinline__ float dpp_ror8(float x) {
    return __int_as_float(__builtin_amdgcn_update_dpp(
        0, __float_as_int(x), 0x128, 0xF, 0xF, true));
}
template<int CTRL>
__device__ __forceinline__ float dpp_mov(float x) {
    return __int_as_float(__builtin_amdgcn_update_dpp(
        0, __float_as_int(x), CTRL, 0xF, 0xF, true));
}
__device__ __forceinline__ float swz_xor16(float x) {
    return __int_as_float(__builtin_amdgcn_ds_swizzle(__float_as_int(x), 0x401F));
}

// ---------------- agg1 (R18: 1024-thr + peeled full/tail rounds) ----------

__global__ __launch_bounds__(1024) void k_agg1(const __half* __restrict__ hs,
                                               const int* __restrict__ offset,
                                               const unsigned* __restrict__ csr,
                                               const float* __restrict__ dinv,
                                               const float* __restrict__ b1,
                                               const float* __restrict__ W2,
                                               float* __restrict__ h2s, int n) {
    int wid  = __builtin_amdgcn_readfirstlane(
                   (int)((blockIdx.x * blockDim.x + threadIdx.x) >> 6));
    int lane = threadIdx.x & 63;
    if (wid >= n) return;
    int off0 = __builtin_amdgcn_readfirstlane(offset[wid]);
    int off1 = __builtin_amdgcn_readfirstlane(offset[wid + 1]);
    int g = lane >> 3, s = lane & 7;
    unsigned sbyte = (unsigned)s << 4;          // s * 16 bytes
    const char* hsB = (const char*)hs;

    float acc[8] = {0.f, 0.f, 0.f, 0.f, 0.f, 0.f, 0.f, 0.f};

    {   // self loop (weight 1)
        f16x8 v = *(const f16x8*)(hsB + (((unsigned)wid) << 7) + sbyte);
        if (g == 0) {
#pragma unroll
            for (int k = 0; k < 8; ++k) acc[k] += (float)v[k];
        }
    }

    int j = off0;
    int nfull = (off1 - off0) >> 5;             // wave-uniform full rounds
    for (int r = 0; r < nfull; ++r, j += 32) {
        unsigned eA = csr[j + g];
        unsigned eB = csr[j + 8 + g];
        unsigned eC = csr[j + 16 + g];
        unsigned eD = csr[j + 24 + g];
        f16x8 vA = *(const f16x8*)(hsB + ((eA & 0x1FFFFu) << 7) + sbyte);
        f16x8 vB = *(const f16x8*)(hsB + ((eB & 0x1FFFFu) << 7) + sbyte);
        f16x8 vC = *(const f16x8*)(hsB + ((eC & 0x1FFFFu) << 7) + sbyte);
        f16x8 vD = *(const f16x8*)(hsB + ((eD & 0x1FFFFu) << 7) + sbyte);
        float wA = (float)__ushort_as_half((unsigned short)(eA >> 17));
        float wB = (float)__ushort_as_half((unsigned short)(eB >> 17));
        float wC = (float)__ushort_as_half((unsigned short)(eC >> 17));
        float wD = (float)__ushort_as_half((unsigned short)(eD >> 17));
#pragma unroll
        for (int k = 0; k < 8; ++k) {
            acc[k] += wA * (float)vA[k];
            acc[k] += wB * (float)vB[k];
            acc[k] += wC * (float)vC[k];
            acc[k] += wD * (float)vD[k];
        }
    }
    if (j < off1) {                             // single checked tail round
        int   i0 = j + g,      i1 = j + 8 + g,  i2 = j + 16 + g, i3 = j + 24 + g;
        bool  k0 = i0 < off1,  k1 = i1 < off1,  k2 = i2 < off1,  k3 = i3 < off1;
        unsigned eA = csr[k0 ? i0 : off1 - 1];
        unsigned eB = csr[k1 ? i1 : off1 - 1];
        unsigned eC = csr[k2 ? i2 : off1 - 1];
        unsigned eD = csr[k3 ? i3 : off1 - 1];
        f16x8 vA = *(const f16x8*)(hsB + ((eA & 0x1FFFFu) << 7) + sbyte);
        f16x8 vB = *(const f16x8*)(hsB + ((eB & 0x1FFFFu) << 7) + sbyte);
        f16x8 vC = *(const f16x8*)(hsB + ((eC & 0x1FFFFu) << 7) + sbyte);
        f16x8 vD = *(const f16x8*)(hsB + ((eD & 0x1FFFFu) << 7) + sbyte);
        float wA = k0 ? (float)__ushort_as_half((unsigned short)(eA >> 17)) : 0.f;
        float wB = k1 ? (float)__ushort_as_half((unsigned short)(eB >> 17)) : 0.f;
        float wC = k2 ? (float)__ushort_as_half((unsigned short)(eC >> 17)) : 0.f;
        float wD = k3 ? (float)__ushort_as_half((unsigned short)(eD >> 17)) : 0.f;
#pragma unroll
        for (int k = 0; k < 8; ++k) {
            acc[k] += wA * (float)vA[k];
            acc[k] += wB * (float)vB[k];
            acc[k] += wC * (float)vC[k];
            acc[k] += wD * (float)vD[k];
        }
    }

    // reduce over groups (lane bits 3,4,5): DPP ror8 + swizzle xor16 + shfl32
#pragma unroll
    for (int k = 0; k < 8; ++k) {
        float t = acc[k];
        t += dpp_ror8(t);
        t += swz_xor16(t);
        t += __shfl_xor(t, 32);
        acc[k] = t;
    }

    float di = dinv[wid];
    float4 bA = ((const float4*)b1)[s * 2], bB = ((const float4*)b1)[s * 2 + 1];
    float4 wA = ((const float4*)W2)[s * 2], wB = ((const float4*)W2)[s * 2 + 1];
    float p = 0.f;
    p += fmaxf(di * acc[0] + bA.x, 0.f) * wA.x;
    p += fmaxf(di * acc[1] + bA.y, 0.f) * wA.y;
    p += fmaxf(di * acc[2] + bA.z, 0.f) * wA.z;
    p += fmaxf(di * acc[3] + bA.w, 0.f) * wA.w;
    p += fmaxf(di * acc[4] + bB.x, 0.f) * wB.x;
    p += fmaxf(di * acc[5] + bB.y, 0.f) * wB.y;
    p += fmaxf(di * acc[6] + bB.z, 0.f) * wB.z;
    p += fmaxf(di * acc[7] + bB.w, 0.f) * wB.w;
    // reduce over s (lane bits 0,1,2): pure DPP
    p += dpp_mov<0xB1>(p);    // quad_perm [1,0,3,2] == xor 1
    p += dpp_mov<0x4E>(p);    // quad_perm [2,3,0,1] == xor 2
    p += dpp_mov<0x141>(p);   // row_half_mirror == xor 4 after 1,2 reduced
    if (lane == 0) h2s[wid] = di * p;
}

// ---------------- agg2 (R18: 1024-thr, body identical) ----------------

__global__ __launch_bounds__(1024) void k_agg2(const float* __restrict__ h2s,
                                               const int* __restrict__ offset,
                                               const unsigned* __restrict__ csr,
                                               const float* __restrict__ dinv,
                                               const float* __restrict__ b2,
                                               float* __restrict__ out, int n) {
    int wid = __builtin_amdgcn_readfirstlane((int)((blockIdx.x * blockDim.x + threadIdx.x) >> 6));
    int lane = threadIdx.x & 63;
    if (wid >= n) return;
    int off0 = __builtin_amdgcn_readfirstlane(offset[wid]);
    int off1 = __builtin_amdgcn_readfirstlane(offset[wid + 1]);
    float di = dinv[wid];
    float p = 0.f;
    for (int e = off0 + lane; e < off1; e += 64) {
        unsigned ed = csr[e];
        p += (float)__ushort_as_half((unsigned short)(ed >> 17)) * h2s[ed & 0x1FFFF];
    }
#pragma unroll
    for (int s = 32; s > 0; s >>= 1) p += __shfl_xor(p, s);
    if (lane == 0) out[wid] = di * (p + h2s[wid]) + b2[0];
}

extern "C" void kernel_launch(void* const* d_in, const int* in_sizes, int n_in,
                              void* d_out, int out_size, void* d_ws, size_t ws_size,
                              hipStream_t stream) {
    const float* x  = (const float*)d_in[0];
    const int*   ei = (const int*)  d_in[1];
    const float* ea = (const float*)d_in[2];
    const float* W1 = (const float*)d_in[3];
    const float* b1 = (const float*)d_in[4];
    const float* W2 = (const float*)d_in[5];
    const float* b2 = (const float*)d_in[6];
    float* out = (float*)d_out;

    const int N  = in_sizes[0] / 128;   // 100000 (must be <= 131072)
    const int E  = in_sizes[2];         // 3200000
    const int E4 = E / 4;
    const int nbl  = (E4 + 4095) / 4096;        // 16384-edge chunks (196)
    const int nbkt = (N + BSIZE - 1) / BSIZE;   // active buckets (196)

    char* p = (char*)d_ws;
    auto alloc = [&](size_t bytes) -> void* {
        void* r = (void*)p;
        p += (bytes + 255) & ~(size_t)255;
        return r;
    };
    int*       hist   = (int*)      alloc((size_t)nbl * NBUCKET * 4);
    int*       histS  = (int*)      alloc((size_t)NBUCKET * nbl * 4);
    int*       tot    = (int*)      alloc((size_t)NBUCKET * 4);
    int*       base   = (int*)      alloc((size_t)(NBUCKET + 1) * 4);
    int2*      binned = (int2*)     alloc((size_t)E * 8);
    unsigned*  csr    = (unsigned*) alloc((size_t)E * 4);
    int*       offset = (int*)      alloc((size_t)(N + 1) * 4);
    float*     dinv   = (float*)    alloc((size_t)N * 4);
    __half*    hs     = (__half*)   alloc((size_t)N * 64 * 2);
    float*     h2s    = (float*)    alloc((size_t)N * 4);

    const int nb_gemm = (N + 63) / 64;
    const int nb_wave = (N * 64 + 1023) / 1024;  // one 64-wide wave per node

    k_hist<<<nbl, 1024, 0, stream>>>(ei + E, hist, E4);
    k_scan_bucket<<<NBUCKET, 256, 0, stream>>>(hist, histS, tot, nbl);
    k_scan_tot<<<1, 256, 0, stream>>>(tot, base);
    k_scatter<<<nbl, 1024, 0, stream>>>(ei, ea, histS, base, binned, E, E4, nbl);
    k_finalize<<<nbkt, 1024, 0, stream>>>(binned, base, csr, offset, dinv, N, E);
    k_gemm_mfma<<<nb_gemm, 256, 0, stream>>>(x, W1, dinv, hs, N);
    k_agg1<<<nb_wave, 1024, 0, stream>>>(hs, offset, csr, dinv, b1, W2, h2s, N);
    k_agg2<<<nb_wave, 1024, 0, stream>>>(h2s, offset, csr, dinv, b2, out, N);
}